// Round 4
// baseline (112.030 us; speedup 1.0000x reference)
//
#include <hip/hip_runtime.h>
#include <math.h>

// Problem constants: B=32, T=1024, D_IN=64, H=128, NH=4, HD=32, R=3
#define TT 1024

// ---------------------------------------------------------------------------
// K1: one block per (b,n) pair. 128 blocks x 1024 threads.
// b = bid & 31, n = bid >> 5 (4 heads of a batch share an XCD -> x[b] L2-local)
// vs round 3: NO phase-B register preload (it spilled at the 128-VGPR cap of
// 1024-thread blocks); phase D unrolled 16-deep (latency hiding without
// pinning 64 dest regs). All other phase structures kept.
// ---------------------------------------------------------------------------
__global__ __launch_bounds__(1024) void k_bn(
    const float* __restrict__ x, const float* __restrict__ theta_w,
    const float* __restrict__ theta_b, const float* __restrict__ ipw,
    const float* __restrict__ ipb, float* __restrict__ u_ws) {
  const int bid = blockIdx.x;
  const int b = bid & 31;
  const int n = bid >> 5;
  const int tid = threadIdx.x;

  __shared__ float s_xs[64];
  __shared__ float s_y[128];
  __shared__ float s_qn[32];
  __shared__ float s_z[128];
  __shared__ float s_rp[8][64];
  __shared__ __align__(16) float s_r[64];
  __shared__ __align__(16) float s_t[TT];
  __shared__ __align__(16) float s_p[TT];
  __shared__ __align__(16) float s_pt[TT];
  __shared__ float s_up[16][64];
  __shared__ float s_red[16];

  const float* __restrict__ xb = x + (size_t)b * TT * 64;

  // ---------------- A ----------------
  if (tid < 64) {
    float acc = xb[(TT - 1) * 64 + tid]
              + 0.5f        * xb[(TT - 2) * 64 + tid]
              + (1.f / 3.f) * xb[(TT - 3) * 64 + tid]
              + 0.25f       * xb[(TT - 4) * 64 + tid];
    s_xs[tid] = acc * (12.f / 25.f);
  }
  __syncthreads();
  if (tid < 128) {  // y = theta*xs + theta_b
    const float* tr = theta_w + tid * 64;
    float acc = theta_b[tid];
    #pragma unroll 16
    for (int d = 0; d < 64; ++d) acc += tr[d] * s_xs[d];
    s_y[tid] = acc;
  }
  __syncthreads();
  if (tid < 512) {  // q_n[gq] = Wq[n*32+gq,:].y + ipb, 16-lane dot
    const int gq = tid >> 4, lq = tid & 15;
    const int e = n * 32 + gq;
    const float* wr = ipw + e * 128 + lq * 8;
    float acc = 0.f;
    #pragma unroll
    for (int u = 0; u < 8; ++u) acc += wr[u] * s_y[lq * 8 + u];
    acc += __shfl_xor(acc, 1);
    acc += __shfl_xor(acc, 2);
    acc += __shfl_xor(acc, 4);
    acc += __shfl_xor(acc, 8);
    if (lq == 0) s_qn[gq] = acc + ipb[e];
  }
  __syncthreads();
  if (tid < 128) {  // z[c] = sum_e Wk[128+n*32+e, c] * q_n[e], bulk-issued
    const int c = tid;
    float acc = 0.f;
    #pragma unroll
    for (int e = 0; e < 32; ++e)
      acc += ipw[(128 + n * 32 + e) * 128 + c] * s_qn[e];
    s_z[c] = acc;
  }
  __syncthreads();
  if (tid < 512) {  // r partials: group gr owns c in [gr*16, gr*16+16)
    const int gr = tid >> 6, d = tid & 63;
    float acc = 0.f;
    #pragma unroll
    for (int cc = 0; cc < 16; ++cc) {
      const int c = gr * 16 + cc;
      acc += theta_w[c * 64 + d] * s_z[c];
    }
    s_rp[gr][d] = acc;
  }
  __syncthreads();
  if (tid < 64) {  // reduce 8 partials, fold 1/sqrt(32)
    float acc = 0.f;
    #pragma unroll
    for (int gr = 0; gr < 8; ++gr) acc += s_rp[gr][tid];
    s_r[tid] = acc * 0.17677669529663687f;
  }
  __syncthreads();

  // ---------------- B: t[j] = x[b,j,:].r ----------------
  {
    const int g = tid >> 4, l = tid & 15;  // 64 row-groups x 16 lanes
    const float4 rv = ((const float4*)s_r)[l];
    #pragma unroll
    for (int it = 0; it < 16; ++it) {
      const int j = it * 64 + g;
      const float4 xv = ((const float4*)(xb + (size_t)j * 64))[l];
      float p = xv.x * rv.x + xv.y * rv.y + xv.z * rv.z + xv.w * rv.w;
      #pragma unroll
      for (int m = 1; m <= 8; m <<= 1) p += __shfl_xor(p, m);
      if (l == 0) s_t[j] = p;
    }
  }
  __syncthreads();

  // ---------------- C: smooth, softmax, Adj^T smooth ----------------
  {
    const int j = tid;
    float acc = 0.f, wsum = 0.f;
    #pragma unroll
    for (int dj = -3; dj <= 3; ++dj) {
      const int jj = j + dj;
      if (jj >= 0 && jj < TT) {
        const float w = 1.f / (1.f + (float)(dj < 0 ? -dj : dj));
        acc += w * s_t[jj];
        wsum += w;
      }
    }
    const float sc = acc / wsum;
    float lmax = sc;
    #pragma unroll
    for (int m = 32; m >= 1; m >>= 1) lmax = fmaxf(lmax, __shfl_xor(lmax, m));
    if ((tid & 63) == 0) s_red[tid >> 6] = lmax;
    __syncthreads();
    float bmax = -1e30f;
    #pragma unroll
    for (int w = 0; w < 16; ++w) bmax = fmaxf(bmax, s_red[w]);
    __syncthreads();
    const float e = expf(sc - bmax);
    s_p[j] = e / wsum;  // pre-divide by rowsum for the Adj^T pass
    float lsum = e;
    #pragma unroll
    for (int m = 32; m >= 1; m >>= 1) lsum += __shfl_xor(lsum, m);
    if ((tid & 63) == 0) s_red[tid >> 6] = lsum;
    __syncthreads();
    float tsum = 0.f;
    #pragma unroll
    for (int w = 0; w < 16; ++w) tsum += s_red[w];
    const float inv_denom = 1.f / tsum;
    float acc2 = 0.f;
    #pragma unroll
    for (int dj = -3; dj <= 3; ++dj) {
      const int s = j + dj;
      if (s >= 0 && s < TT)
        acc2 += (1.f / (1.f + (float)(dj < 0 ? -dj : dj))) * s_p[s];
    }
    s_pt[j] = acc2 * inv_denom;
  }
  __syncthreads();

  // ---------------- D: u[d] = sum_j p~[j] x[b,j,d] ----------------
  {
    const int jp = tid >> 6, d = tid & 63;  // 16 chunks x 64 d
    const float* xr = xb + (size_t)(jp * 64) * 64 + d;
    float acc = 0.f;
    #pragma unroll 16
    for (int jj = 0; jj < 64; ++jj)
      acc += s_pt[jp * 64 + jj] * xr[jj * 64];
    s_up[jp][d] = acc;
  }
  __syncthreads();
  if (tid < 64) {  // chunk reduce, ascending
    const int d = tid;
    float acc = 0.f;
    #pragma unroll
    for (int c = 0; c < 16; ++c) acc += s_up[c][d];
    u_ws[((size_t)b * 4 + n) * 64 + d] = acc;
  }
}

// ---------------------------------------------------------------------------
// K2: tail per b. 32 blocks x 128 threads.
// ---------------------------------------------------------------------------
__global__ __launch_bounds__(128) void k_tail(
    const float* __restrict__ u_in, const float* __restrict__ theta_w,
    const float* __restrict__ theta_b, const float* __restrict__ ipw,
    const float* __restrict__ ipb, const float* __restrict__ Wout,
    const float* __restrict__ outb, const float* __restrict__ ln_g,
    const float* __restrict__ ln_b, const float* __restrict__ w1,
    const float* __restrict__ b1, const float* __restrict__ w2,
    const float* __restrict__ b2, float* __restrict__ out) {
  const int b = blockIdx.x;
  const int tid = threadIdx.x;
  __shared__ float s_u[256];      // [n][d]
  __shared__ float s_w[4][128];   // theta*u + theta_b per head
  __shared__ float s_o[128], s_ln[128], s_hid[128], s_red[2];

  #pragma unroll
  for (int rep = 0; rep < 2; ++rep) {
    const int idx = tid + rep * 128;
    s_u[idx] = u_in[b * 256 + idx];
  }
  __syncthreads();
  // w[n][c] = theta[c,:].u(n) + theta_b[c]
  #pragma unroll
  for (int rep = 0; rep < 4; ++rep) {
    const int idx = tid + rep * 128;
    const int n = idx >> 7, c = idx & 127;
    const float* tr = theta_w + c * 64;
    const float* un = &s_u[n * 64];
    float acc = theta_b[c];
    #pragma unroll 16
    for (int d = 0; d < 64; ++d) acc += tr[d] * un[d];
    s_w[n][c] = acc;
  }
  __syncthreads();
  // o_e = Wv[256+e,:].w(n(e)) + ipb[256+e]
  {
    const int e = tid, n = e >> 5;
    const float* wr = ipw + (256 + e) * 128;
    const float* wn = s_w[n];
    float acc = ipb[256 + e];
    #pragma unroll 16
    for (int c = 0; c < 128; ++c) acc += wr[c] * wn[c];
    s_o[e] = acc;
  }
  __syncthreads();
  const int e = tid;
  float a = outb[e];
  {
    const float* wr = Wout + e * 128;
    #pragma unroll 16
    for (int f = 0; f < 128; ++f) a += wr[f] * s_o[f];
  }
  float sum = a;
  #pragma unroll
  for (int m = 32; m >= 1; m >>= 1) sum += __shfl_xor(sum, m);
  if ((e & 63) == 0) s_red[e >> 6] = sum;
  __syncthreads();
  const float mu = (s_red[0] + s_red[1]) * (1.f / 128.f);
  __syncthreads();
  const float d = a - mu;
  float sq = d * d;
  #pragma unroll
  for (int m = 32; m >= 1; m >>= 1) sq += __shfl_xor(sq, m);
  if ((e & 63) == 0) s_red[e >> 6] = sq;
  __syncthreads();
  const float var = (s_red[0] + s_red[1]) * (1.f / 128.f);
  const float ln = d / sqrtf(var + 1e-5f) * ln_g[e] + ln_b[e];
  s_ln[e] = ln;
  __syncthreads();
  float h = b1[e];
  {
    const float* w1r = w1 + e * 128;
    #pragma unroll 16
    for (int f = 0; f < 128; ++f) h += w1r[f] * s_ln[f];
  }
  h = 0.5f * h * (1.f + erff(h * 0.70710678118654752f));
  s_hid[e] = h;
  __syncthreads();
  if (e < 2) {
    float acc = b2[e];
    const float* w2r = w2 + e * 128;
    #pragma unroll 16
    for (int f = 0; f < 128; ++f) acc += w2r[f] * s_hid[f];
    out[b * 2 + e] = acc;
  }
}

extern "C" void kernel_launch(void* const* d_in, const int* in_sizes, int n_in,
                              void* d_out, int out_size, void* d_ws, size_t ws_size,
                              hipStream_t stream) {
  const float* x       = (const float*)d_in[0];
  const float* theta_w = (const float*)d_in[1];
  const float* theta_b = (const float*)d_in[2];
  const float* ipw     = (const float*)d_in[3];
  const float* ipb     = (const float*)d_in[4];
  const float* outw    = (const float*)d_in[5];
  const float* outb    = (const float*)d_in[6];
  const float* ln_g    = (const float*)d_in[7];
  const float* ln_b    = (const float*)d_in[8];
  const float* w1      = (const float*)d_in[9];
  const float* b1      = (const float*)d_in[10];
  const float* w2      = (const float*)d_in[11];
  const float* b2      = (const float*)d_in[12];

  float* u_ws = (float*)d_ws;  // 32*4*64 = 8192 floats

  k_bn  <<<128, 1024, 0, stream>>>(x, theta_w, theta_b, ipw, ipb, u_ws);
  k_tail<<< 32,  128, 0, stream>>>(u_ws, theta_w, theta_b, ipw, ipb, outw, outb,
                                   ln_g, ln_b, w1, b1, w2, b2, (float*)d_out);
}

// Round 5
// 109.708 us; speedup vs baseline: 1.0212x; 1.0212x over previous
//
#include <hip/hip_runtime.h>
#include <math.h>

// Problem constants: B=32, T=1024, D_IN=64, H=128, NH=4, HD=32, R=3
#define TT 1024

// ---------------------------------------------------------------------------
// Softmax factorization: with sc_s the smoothed score,
//   p~_j = [sum_dj w*exp(sc_{j+dj})/wsum_{j+dj}] / [sum_s exp(sc_s)]
// (the usual max-subtraction cancels exactly). So each 128-row chunk can
// compute unnormalized U_part[n][d] = sum_{j in chunk} p~u_j x[j][d] and
// S_part[n] = sum_{s in chunk} exp(sc_s) with only a +-8 row halo.
// K1: 256 blocks = (chunk c in 8) x (batch b in 32), 512 threads.
//     bid = c*32 + b  ->  XCD = b&7 for all chunks of b (x[b] stays L2-local).
// K2: verified 32-block tail; reduces 16 ascending 64-row partials, divides
//     by S, then the verbatim epilogue.
// ---------------------------------------------------------------------------

__device__ __forceinline__ void sc_ep(const float* __restrict__ tn,
                                      float* __restrict__ en,
                                      float* __restrict__ pn,
                                      int lr, int jg) {
  float acc = 0.f, wsum = 0.f;
  #pragma unroll
  for (int dj = -3; dj <= 3; ++dj) {
    const int js = jg + dj;
    if (js >= 0 && js < TT) {
      const float w = 1.f / (1.f + (float)(dj < 0 ? -dj : dj));
      acc += w * tn[lr + dj];
      wsum += w;
    }
  }
  const float sc = acc / wsum;
  const float e = expf(sc);   // sc << 1 here; unsubtracted exp is safe
  en[lr] = e;
  pn[lr] = e / wsum;          // pre-divide by adj rowsum for the Adj^T pass
}

__global__ __launch_bounds__(512) void k_chunk(
    const float* __restrict__ x, const float* __restrict__ theta_w,
    const float* __restrict__ theta_b, const float* __restrict__ ipw,
    const float* __restrict__ ipb, float* __restrict__ up_ws,
    float* __restrict__ s_ws) {
  const int bid = blockIdx.x;
  const int b = bid & 31;        // batch
  const int c = bid >> 5;        // 128-row chunk index, 0..7
  const int tid = threadIdx.x;

  __shared__ float s_x[144][65];  // pad 65: (j+d)%32 banks -> 2-way max (free)
  __shared__ float s_xs[64];
  __shared__ float s_y[128];
  __shared__ float s_q[128];
  __shared__ float s_z[4][128];
  __shared__ float s_r[4][64];
  __shared__ float s_t[4][144];
  __shared__ float s_e[4][144];
  __shared__ float s_p[4][144];
  __shared__ float s_pt[4][128];
  __shared__ float s_sp[4][2];

  const float* __restrict__ xb = x + (size_t)b * TT * 64;
  const int j0 = c * 128 - 8;    // staged rows [j0, j0+144), clamped

  // ---- stage 144 x-rows into LDS (clamped halo; out-of-range rows are
  //      computed-but-never-consumed thanks to global-j guards below)
  #pragma unroll
  for (int k = 0; k < 5; ++k) {
    const int i4 = tid + k * 512;
    if (i4 < 144 * 16) {
      const int lr = i4 >> 4, col = (i4 & 15) * 4;
      int j = j0 + lr;
      j = j < 0 ? 0 : (j > TT - 1 ? TT - 1 : j);
      const float4 v = *(const float4*)(xb + (size_t)j * 64 + col);
      s_x[lr][col + 0] = v.x;
      s_x[lr][col + 1] = v.y;
      s_x[lr][col + 2] = v.z;
      s_x[lr][col + 3] = v.w;
    }
  }

  // ---------------- A: prologue (verified mappings, duplicated per chunk)
  if (tid < 64) {
    float acc = xb[(TT - 1) * 64 + tid]
              + 0.5f        * xb[(TT - 2) * 64 + tid]
              + (1.f / 3.f) * xb[(TT - 3) * 64 + tid]
              + 0.25f       * xb[(TT - 4) * 64 + tid];
    s_xs[tid] = acc * (12.f / 25.f);
  }
  __syncthreads();
  if (tid < 128) {  // y = theta*xs + theta_b
    const float* tr = theta_w + tid * 64;
    float acc = theta_b[tid];
    #pragma unroll 16
    for (int d = 0; d < 64; ++d) acc += tr[d] * s_xs[d];
    s_y[tid] = acc;
  }
  __syncthreads();
  if (tid < 256) {  // q_e = Wq[e,:].y + ipb[e], 16-lane dots (verified)
    const int g = tid >> 4, l = tid & 15;
    for (int pass = 0; pass < 8; ++pass) {
      const int e = pass * 16 + g;
      const float* wr = ipw + e * 128 + l * 8;
      float acc = 0.f;
      #pragma unroll
      for (int u = 0; u < 8; ++u) acc += wr[u] * s_y[l * 8 + u];
      acc += __shfl_xor(acc, 1);
      acc += __shfl_xor(acc, 2);
      acc += __shfl_xor(acc, 4);
      acc += __shfl_xor(acc, 8);
      if (l == 0) s_q[e] = acc + ipb[e];
    }
  }
  __syncthreads();
  {  // z[n][cc] = sum_e Wk[128+n*32+e, cc] * q[n*32+e]
    const int n = tid >> 7, cc = tid & 127;
    const float* qn = &s_q[n * 32];
    float acc = 0.f;
    #pragma unroll
    for (int e = 0; e < 32; ++e)
      acc += ipw[(128 + n * 32 + e) * 128 + cc] * qn[e];
    s_z[n][cc] = acc;
  }
  __syncthreads();
  if (tid < 256) {  // r[n][d] = sum_c theta[c,d] z[n][c], fold 1/sqrt(32)
    const int n = tid >> 6, d = tid & 63;
    const float* zn = s_z[n];
    float acc = 0.f;
    #pragma unroll 16
    for (int cidx = 0; cidx < 128; ++cidx)
      acc += theta_w[cidx * 64 + d] * zn[cidx];
    s_r[n][d] = acc * 0.17677669529663687f;
  }
  __syncthreads();

  // ---------------- t[n][lr] = x[j0+lr,:] . r[n,:] from LDS ----------------
  {
    const int n = tid >> 7, lr = tid & 127;
    const float* xr = s_x[lr];
    const float* rn = s_r[n];
    float acc = 0.f;
    #pragma unroll 16
    for (int d = 0; d < 64; ++d) acc += xr[d] * rn[d];
    s_t[n][lr] = acc;
  }
  if (tid < 64) {  // lr 128..143
    const int n = tid >> 4, lr = 128 + (tid & 15);
    const float* xr = s_x[lr];
    const float* rn = s_r[n];
    float acc = 0.f;
    #pragma unroll 16
    for (int d = 0; d < 64; ++d) acc += xr[d] * rn[d];
    s_t[n][lr] = acc;
  }
  __syncthreads();

  // ---------------- sc -> exp, p (lr in [5,139) i.e. own chunk +-3) -------
  {
    const int n = tid >> 7, lr = 5 + (tid & 127);
    sc_ep(s_t[n], s_e[n], s_p[n], lr, j0 + lr);
  }
  if (tid < 24) {  // lr 133..138
    const int n = tid / 6, lr = 133 + tid % 6;
    sc_ep(s_t[n], s_e[n], s_p[n], lr, j0 + lr);
  }
  __syncthreads();

  // ---------------- p~u (own chunk) + S_part reduction --------------------
  {
    const int n = tid >> 7, lj = tid & 127;
    const int lr = 8 + lj, jg = j0 + lr;  // = c*128 + lj
    float acc = 0.f;
    #pragma unroll
    for (int dj = -3; dj <= 3; ++dj) {
      const int s = jg + dj;
      if (s >= 0 && s < TT)
        acc += (1.f / (1.f + (float)(dj < 0 ? -dj : dj))) * s_p[n][lr + dj];
    }
    s_pt[n][lj] = acc;
    float e = s_e[n][lr];
    #pragma unroll
    for (int m = 32; m >= 1; m >>= 1) e += __shfl_xor(e, m);
    if ((tid & 63) == 0) s_sp[n][(tid >> 6) & 1] = e;
  }
  __syncthreads();

  // ---------------- u partials over two 64-row halves ---------------------
  {
    const int h = tid >> 8, nn = (tid >> 6) & 3, d = tid & 63;
    float acc = 0.f;
    #pragma unroll 16
    for (int jj = 0; jj < 64; ++jj)
      acc += s_pt[nn][h * 64 + jj] * s_x[8 + h * 64 + jj][d];
    // 64-row partial index = c*2+h, ascending in j (matches verified reduce)
    up_ws[((size_t)b * 16 + (c * 2 + h)) * 256 + nn * 64 + d] = acc;
  }
  if (tid < 4)
    s_ws[((size_t)b * 8 + c) * 4 + tid] = s_sp[tid][0] + s_sp[tid][1];
}

// ---------------------------------------------------------------------------
// K2: tail per b. 32 blocks x 128 threads. Verified epilogue; the partial
// reduce now divides by S = sum of chunk exp-sums.
// ---------------------------------------------------------------------------
__global__ __launch_bounds__(128) void k_tail(
    const float* __restrict__ up_in, const float* __restrict__ s_in,
    const float* __restrict__ theta_w, const float* __restrict__ theta_b,
    const float* __restrict__ ipw, const float* __restrict__ ipb,
    const float* __restrict__ Wout, const float* __restrict__ outb,
    const float* __restrict__ ln_g, const float* __restrict__ ln_b,
    const float* __restrict__ w1, const float* __restrict__ b1,
    const float* __restrict__ w2, const float* __restrict__ b2,
    float* __restrict__ out) {
  const int b = blockIdx.x;
  const int tid = threadIdx.x;
  __shared__ float s_u[256];      // [n][d]
  __shared__ float s_w[4][128];   // theta*u + theta_b per head
  __shared__ float s_o[128], s_ln[128], s_hid[128], s_red[2];

  // reduce 16 ascending 64-row partials, then normalize by S
  #pragma unroll
  for (int rep = 0; rep < 2; ++rep) {
    const int idx = tid + rep * 128;
    const int n = idx >> 6;
    float acc = 0.f;
    #pragma unroll
    for (int cc = 0; cc < 16; ++cc) acc += up_in[(b * 16 + cc) * 256 + idx];
    float S = 0.f;
    #pragma unroll
    for (int cc = 0; cc < 8; ++cc) S += s_in[(b * 8 + cc) * 4 + n];
    s_u[idx] = acc / S;
  }
  __syncthreads();
  // w[n][c] = theta[c,:].u(n) + theta_b[c]
  #pragma unroll
  for (int rep = 0; rep < 4; ++rep) {
    const int idx = tid + rep * 128;
    const int n = idx >> 7, c = idx & 127;
    const float* tr = theta_w + c * 64;
    const float* un = &s_u[n * 64];
    float acc = theta_b[c];
    #pragma unroll 16
    for (int d = 0; d < 64; ++d) acc += tr[d] * un[d];
    s_w[n][c] = acc;
  }
  __syncthreads();
  // o_e = Wv[256+e,:].w(n(e)) + ipb[256+e]
  {
    const int e = tid, n = e >> 5;
    const float* wr = ipw + (256 + e) * 128;
    const float* wn = s_w[n];
    float acc = ipb[256 + e];
    #pragma unroll 16
    for (int c = 0; c < 128; ++c) acc += wr[c] * wn[c];
    s_o[e] = acc;
  }
  __syncthreads();
  const int e = tid;
  float a = outb[e];
  {
    const float* wr = Wout + e * 128;
    #pragma unroll 16
    for (int f = 0; f < 128; ++f) a += wr[f] * s_o[f];
  }
  float sum = a;
  #pragma unroll
  for (int m = 32; m >= 1; m >>= 1) sum += __shfl_xor(sum, m);
  if ((e & 63) == 0) s_red[e >> 6] = sum;
  __syncthreads();
  const float mu = (s_red[0] + s_red[1]) * (1.f / 128.f);
  __syncthreads();
  const float d = a - mu;
  float sq = d * d;
  #pragma unroll
  for (int m = 32; m >= 1; m >>= 1) sq += __shfl_xor(sq, m);
  if ((e & 63) == 0) s_red[e >> 6] = sq;
  __syncthreads();
  const float var = (s_red[0] + s_red[1]) * (1.f / 128.f);
  const float ln = d / sqrtf(var + 1e-5f) * ln_g[e] + ln_b[e];
  s_ln[e] = ln;
  __syncthreads();
  float h = b1[e];
  {
    const float* w1r = w1 + e * 128;
    #pragma unroll 16
    for (int f = 0; f < 128; ++f) h += w1r[f] * s_ln[f];
  }
  h = 0.5f * h * (1.f + erff(h * 0.70710678118654752f));
  s_hid[e] = h;
  __syncthreads();
  if (e < 2) {
    float acc = b2[e];
    const float* w2r = w2 + e * 128;
    #pragma unroll 16
    for (int f = 0; f < 128; ++f) acc += w2r[f] * s_hid[f];
    out[b * 2 + e] = acc;
  }
}

extern "C" void kernel_launch(void* const* d_in, const int* in_sizes, int n_in,
                              void* d_out, int out_size, void* d_ws, size_t ws_size,
                              hipStream_t stream) {
  const float* x       = (const float*)d_in[0];
  const float* theta_w = (const float*)d_in[1];
  const float* theta_b = (const float*)d_in[2];
  const float* ipw     = (const float*)d_in[3];
  const float* ipb     = (const float*)d_in[4];
  const float* outw    = (const float*)d_in[5];
  const float* outb    = (const float*)d_in[6];
  const float* ln_g    = (const float*)d_in[7];
  const float* ln_b    = (const float*)d_in[8];
  const float* w1      = (const float*)d_in[9];
  const float* b1      = (const float*)d_in[10];
  const float* w2      = (const float*)d_in[11];
  const float* b2      = (const float*)d_in[12];

  float* up_ws = (float*)d_ws;            // 32*16*256 = 131072 floats
  float* s_ws  = (float*)d_ws + 131072;   // 32*8*4    = 1024 floats

  k_chunk<<<256, 512, 0, stream>>>(x, theta_w, theta_b, ipw, ipb, up_ws, s_ws);
  k_tail <<< 32, 128, 0, stream>>>(up_ws, s_ws, theta_w, theta_b, ipw, ipb,
                                   outw, outb, ln_g, ln_b, w1, b1, w2, b2,
                                   (float*)d_out);
}